// Round 4
// baseline (174.459 us; speedup 1.0000x reference)
//
#include <hip/hip_runtime.h>

// DeepClusterLoss: out[0]=total, out[1]=recon_loss, out[2]=cluster_loss
// recon_loss = sum((recon_x - x)^2)   over [N=1e6, D=64] f32
// cluster_loss = sum((x - centers[assign])^2)
// ALPHA = BETA = 1.0

#define NROWS  1000000
#define DCOLS  64
#define BLOCK  256
#define GRID   3125               // 62500 groups / 3125 = 20 per block = 5 chunks of 4, exact
#define CHUNK  (GRID * 1024)      // float stride per k-step (GRID groups * 16 rows * 64 cols)
#define ARSTEP (GRID * 16)        // assignment-row stride per k-step

// sched_group_barrier masks (LLVM SchedGroupMask)
#define SGB_VALU      0x002
#define SGB_VMEM_READ 0x020

__global__ void dcl_zero_out(float* __restrict__ out) {
    out[0] = 0.0f;
    out[1] = 0.0f;
    out[2] = 0.0f;
}

__device__ __forceinline__ float sq4(float4 a, float4 b) {
    float d0 = a.x - b.x, d1 = a.y - b.y, d2 = a.z - b.z, d3 = a.w - b.w;
    return d0 * d0 + d1 * d1 + d2 * d2 + d3 * d3;
}

__global__ __launch_bounds__(BLOCK) void dcl_main(
    const float* __restrict__ recon_x,
    const float* __restrict__ x,
    const int* __restrict__ assign,
    const float* __restrict__ centers,
    float* __restrict__ out)
{
    const int t   = threadIdx.x;
    const int r   = t >> 4;        // row within 16-row group: 0..15
    const int col = (t & 15) * 4;  // float4 slot within row

    const int fbase = blockIdx.x * 1024 + r * 64 + col;  // float index base
    const int abase = blockIdx.x * 16 + r;               // assignment index base

    // 4 independent accumulator pairs to widen the FP dependence graph
    float ra0 = 0.f, ra1 = 0.f, ra2 = 0.f, ra3 = 0.f;
    float ca0 = 0.f, ca1 = 0.f, ca2 = 0.f, ca3 = 0.f;

    // software-pipelined assignment prefetch: center addresses for chunk k
    // are ready before the chunk's load batch is issued
    int c0 = assign[abase + 0 * ARSTEP];
    int c1 = assign[abase + 1 * ARSTEP];
    int c2 = assign[abase + 2 * ARSTEP];
    int c3 = assign[abase + 3 * ARSTEP];

    #pragma unroll
    for (int k = 0; k < 20; k += 4) {
        const int f0 = fbase + (k + 0) * CHUNK;
        const int f1 = fbase + (k + 1) * CHUNK;
        const int f2 = fbase + (k + 2) * CHUNK;
        const int f3 = fbase + (k + 3) * CHUNK;

        // ---- one batch: 12 data loads + 4 next-assign loads ----
        const float4 xv0 = *(const float4*)(x + f0);
        const float4 xv1 = *(const float4*)(x + f1);
        const float4 xv2 = *(const float4*)(x + f2);
        const float4 xv3 = *(const float4*)(x + f3);
        const float4 rv0 = *(const float4*)(recon_x + f0);
        const float4 rv1 = *(const float4*)(recon_x + f1);
        const float4 rv2 = *(const float4*)(recon_x + f2);
        const float4 rv3 = *(const float4*)(recon_x + f3);
        const float4 cv0 = *(const float4*)(centers + c0 * DCOLS + col);
        const float4 cv1 = *(const float4*)(centers + c1 * DCOLS + col);
        const float4 cv2 = *(const float4*)(centers + c2 * DCOLS + col);
        const float4 cv3 = *(const float4*)(centers + c3 * DCOLS + col);

        const int nk = (k + 4) % 20;  // wraps on last iter; harmless
        const int n0 = assign[abase + (nk + 0) * ARSTEP];
        const int n1 = assign[abase + (nk + 1) * ARSTEP];
        const int n2 = assign[abase + (nk + 2) * ARSTEP];
        const int n3 = assign[abase + (nk + 3) * ARSTEP];

        ra0 += sq4(rv0, xv0);
        ra1 += sq4(rv1, xv1);
        ra2 += sq4(rv2, xv2);
        ra3 += sq4(rv3, xv3);
        ca0 += sq4(xv0, cv0);
        ca1 += sq4(xv1, cv1);
        ca2 += sq4(xv2, cv2);
        ca3 += sq4(xv3, cv3);

        c0 = n0; c1 = n1; c2 = n2; c3 = n3;

        // compile-time schedule template: cluster the 16 VMEM reads as a
        // batch, then the VALU block — prevents the scheduler from
        // serializing into load->wait->consume (VGPR=36 pathology).
        __builtin_amdgcn_sched_group_barrier(SGB_VMEM_READ, 16, 0);
        __builtin_amdgcn_sched_group_barrier(SGB_VALU, 96, 0);
    }

    float racc = (ra0 + ra1) + (ra2 + ra3);
    float cacc = (ca0 + ca1) + (ca2 + ca3);

    // wave-64 butterfly reduce
    #pragma unroll
    for (int off = 32; off > 0; off >>= 1) {
        racc += __shfl_down(racc, off);
        cacc += __shfl_down(cacc, off);
    }

    __shared__ float wsum_r[BLOCK / 64];
    __shared__ float wsum_c[BLOCK / 64];
    const int wave = t >> 6;
    if ((t & 63) == 0) {
        wsum_r[wave] = racc;
        wsum_c[wave] = cacc;
    }
    __syncthreads();

    if (t == 0) {
        float R = 0.0f, C = 0.0f;
        #pragma unroll
        for (int w = 0; w < BLOCK / 64; ++w) { R += wsum_r[w]; C += wsum_c[w]; }
        atomicAdd(&out[1], R);
        atomicAdd(&out[2], C);
        atomicAdd(&out[0], R + C);   // ALPHA=BETA=1
    }
}

extern "C" void kernel_launch(void* const* d_in, const int* in_sizes, int n_in,
                              void* d_out, int out_size, void* d_ws, size_t ws_size,
                              hipStream_t stream) {
    const float* recon_x = (const float*)d_in[0];
    const float* x       = (const float*)d_in[1];
    const int*   assign  = (const int*)d_in[2];
    const float* centers = (const float*)d_in[3];
    float* out = (float*)d_out;

    dcl_zero_out<<<1, 1, 0, stream>>>(out);
    dcl_main<<<GRID, BLOCK, 0, stream>>>(recon_x, x, assign, centers, out);
}

// Round 5
// 113.696 us; speedup vs baseline: 1.5344x; 1.5344x over previous
//
#include <hip/hip_runtime.h>

// DeepClusterLoss: out[0]=total, out[1]=recon_loss, out[2]=cluster_loss
// recon_loss = sum((recon_x - x)^2)   over [N=1e6, D=64] f32
// cluster_loss = sum((x - centers[assign])^2)
// ALPHA = BETA = 1.0

#define NROWS 1000000
#define DCOLS 64
#define BLOCK 256
#define GRID  2500
#define SPAN  25   // row-groups per block, contiguous: 2500*25 = 62500 groups exact

typedef float f32x4 __attribute__((ext_vector_type(4)));

__global__ void dcl_zero_out(float* __restrict__ out) {
    out[1] = 0.0f;
    out[2] = 0.0f;
}

__global__ void dcl_finalize(float* __restrict__ out) {
    out[0] = out[1] + out[2];   // ALPHA=BETA=1
}

__device__ __forceinline__ float sq4(f32x4 a, f32x4 b) {
    float d0 = a.x - b.x, d1 = a.y - b.y, d2 = a.z - b.z, d3 = a.w - b.w;
    return d0 * d0 + d1 * d1 + d2 * d2 + d3 * d3;
}

__global__ __launch_bounds__(BLOCK) void dcl_main(
    const float* __restrict__ recon_x,
    const float* __restrict__ x,
    const int* __restrict__ assign,
    const float* __restrict__ centers,
    float* __restrict__ out)
{
    const int t   = threadIdx.x;
    const int r   = t >> 4;        // row within 16-row group: 0..15
    const int col = (t & 15) * 4;  // float4 slot within row
    const int g0  = blockIdx.x * SPAN;

    // two independent accumulator pairs
    float ra0 = 0.f, ra1 = 0.f, ca0 = 0.f, ca1 = 0.f;

    #pragma unroll 5
    for (int k = 0; k < SPAN; ++k) {
        const int g   = g0 + k;
        const int row = g * 16 + r;
        const int c   = assign[row];
        const int fb  = g * 1024 + r * 64 + col;

        // nontemporal: stream straight from HBM, don't allocate in L2/L3
        const f32x4 xv = __builtin_nontemporal_load((const f32x4*)(x + fb));
        const f32x4 rv = __builtin_nontemporal_load((const f32x4*)(recon_x + fb));
        const f32x4 cv = *(const f32x4*)(centers + c * DCOLS + col);

        if (k & 1) {
            ra1 += sq4(rv, xv);
            ca1 += sq4(xv, cv);
        } else {
            ra0 += sq4(rv, xv);
            ca0 += sq4(xv, cv);
        }
    }

    float racc = ra0 + ra1;
    float cacc = ca0 + ca1;

    // wave-64 butterfly reduce
    #pragma unroll
    for (int off = 32; off > 0; off >>= 1) {
        racc += __shfl_down(racc, off);
        cacc += __shfl_down(cacc, off);
    }

    __shared__ float wsum_r[BLOCK / 64];
    __shared__ float wsum_c[BLOCK / 64];
    const int wave = t >> 6;
    if ((t & 63) == 0) {
        wsum_r[wave] = racc;
        wsum_c[wave] = cacc;
    }
    __syncthreads();

    if (t == 0) {
        float R = 0.0f, C = 0.0f;
        #pragma unroll
        for (int w = 0; w < BLOCK / 64; ++w) { R += wsum_r[w]; C += wsum_c[w]; }
        atomicAdd(&out[1], R);
        atomicAdd(&out[2], C);
    }
}

extern "C" void kernel_launch(void* const* d_in, const int* in_sizes, int n_in,
                              void* d_out, int out_size, void* d_ws, size_t ws_size,
                              hipStream_t stream) {
    const float* recon_x = (const float*)d_in[0];
    const float* x       = (const float*)d_in[1];
    const int*   assign  = (const int*)d_in[2];
    const float* centers = (const float*)d_in[3];
    float* out = (float*)d_out;

    dcl_zero_out<<<1, 1, 0, stream>>>(out);
    dcl_main<<<GRID, BLOCK, 0, stream>>>(recon_x, x, assign, centers, out);
    dcl_finalize<<<1, 1, 0, stream>>>(out);
}

// Round 6
// 112.143 us; speedup vs baseline: 1.5557x; 1.0138x over previous
//
#include <hip/hip_runtime.h>

// DeepClusterLoss: out[0]=total, out[1]=recon_loss, out[2]=cluster_loss
// recon_loss = sum((recon_x - x)^2)   over [N=1e6, D=64] f32
// cluster_loss = sum((x - centers[assign])^2)
// ALPHA = BETA = 1.0

#define NROWS 1000000
#define DCOLS 64
#define BLOCK 256
#define GRID  2500
#define SPAN  25   // row-groups per block, contiguous: 2500*25 = 62500 groups exact

typedef float f32x4 __attribute__((ext_vector_type(4)));

__global__ void dcl_zero_out(float* __restrict__ out) {
    out[1] = 0.0f;
    out[2] = 0.0f;
}

__global__ void dcl_finalize(float* __restrict__ out) {
    out[0] = out[1] + out[2];   // ALPHA=BETA=1
}

__device__ __forceinline__ float sq4(f32x4 a, f32x4 b) {
    float d0 = a.x - b.x, d1 = a.y - b.y, d2 = a.z - b.z, d3 = a.w - b.w;
    return d0 * d0 + d1 * d1 + d2 * d2 + d3 * d3;
}

__global__ __launch_bounds__(BLOCK) void dcl_main(
    const float* __restrict__ recon_x,
    const float* __restrict__ x,
    const int* __restrict__ assign,
    const float* __restrict__ centers,
    float* __restrict__ out)
{
    const int t   = threadIdx.x;
    const int r   = t >> 4;        // row within 16-row group: 0..15
    const int col = (t & 15) * 4;  // float4 slot within row
    const int g0  = blockIdx.x * SPAN;

    const int fbase = g0 * 1024 + r * 64 + col;
    const int abase = g0 * 16 + r;

    float ra0 = 0.f, ra1 = 0.f, ca0 = 0.f, ca1 = 0.f;

    // ---- depth-2 software pipeline: loads for k+2 issued while computing k.
    // Named-variable rotation (no runtime-indexed arrays -> stays in VGPRs).
    f32x4 xa = __builtin_nontemporal_load((const f32x4*)(x       + fbase));
    f32x4 ra = __builtin_nontemporal_load((const f32x4*)(recon_x + fbase));
    int   ca = assign[abase];
    f32x4 xb = __builtin_nontemporal_load((const f32x4*)(x       + fbase + 1024));
    f32x4 rb = __builtin_nontemporal_load((const f32x4*)(recon_x + fbase + 1024));
    int   cb = assign[abase + 16];

    #pragma unroll
    for (int k = 0; k < SPAN; ++k) {
        f32x4 xn, rn;
        int   cn;
        if (k + 2 < SPAN) {   // compile-time (full unroll)
            const int fb2 = fbase + (k + 2) * 1024;
            xn = __builtin_nontemporal_load((const f32x4*)(x       + fb2));
            rn = __builtin_nontemporal_load((const f32x4*)(recon_x + fb2));
            cn = assign[abase + (k + 2) * 16];
        } else {
            xn = xa; rn = ra; cn = 0;  // dead values, keep types defined
        }

        const f32x4 cv = *(const f32x4*)(centers + ca * DCOLS + col);

        if (k & 1) {
            ra1 += sq4(ra, xa);
            ca1 += sq4(xa, cv);
        } else {
            ra0 += sq4(ra, xa);
            ca0 += sq4(xa, cv);
        }

        xa = xb; ra = rb; ca = cb;
        xb = xn; rb = rn; cb = cn;
    }

    float racc = ra0 + ra1;
    float cacc = ca0 + ca1;

    // wave-64 butterfly reduce
    #pragma unroll
    for (int off = 32; off > 0; off >>= 1) {
        racc += __shfl_down(racc, off);
        cacc += __shfl_down(cacc, off);
    }

    __shared__ float wsum_r[BLOCK / 64];
    __shared__ float wsum_c[BLOCK / 64];
    const int wave = t >> 6;
    if ((t & 63) == 0) {
        wsum_r[wave] = racc;
        wsum_c[wave] = cacc;
    }
    __syncthreads();

    if (t == 0) {
        float R = 0.0f, C = 0.0f;
        #pragma unroll
        for (int w = 0; w < BLOCK / 64; ++w) { R += wsum_r[w]; C += wsum_c[w]; }
        atomicAdd(&out[1], R);
        atomicAdd(&out[2], C);
    }
}

extern "C" void kernel_launch(void* const* d_in, const int* in_sizes, int n_in,
                              void* d_out, int out_size, void* d_ws, size_t ws_size,
                              hipStream_t stream) {
    const float* recon_x = (const float*)d_in[0];
    const float* x       = (const float*)d_in[1];
    const int*   assign  = (const int*)d_in[2];
    const float* centers = (const float*)d_in[3];
    float* out = (float*)d_out;

    dcl_zero_out<<<1, 1, 0, stream>>>(out);
    dcl_main<<<GRID, BLOCK, 0, stream>>>(recon_x, x, assign, centers, out);
    dcl_finalize<<<1, 1, 0, stream>>>(out);
}

// Round 8
// 84.496 us; speedup vs baseline: 2.0647x; 1.3272x over previous
//
#include <hip/hip_runtime.h>

// DeepClusterLoss: out[0]=total, out[1]=recon_loss, out[2]=cluster_loss
// recon_loss = sum((recon_x - x)^2)   over [N=1e6, D=64] f32
// cluster_loss = sum((x - centers[assign])^2)
// ALPHA = BETA = 1.0
//
// Structure: fine-grained blocks (GRID=12500, 40 KB each) so backfill keeps
// all CUs fed to the end (R6 showed a ~30% drain tail with 200 KB blocks).
// No atomics: per-block partials -> d_ws, one-block finalize reduction.

#define NROWS 1000000
#define DCOLS 64
#define BLOCK 256
#define GRID  12500
#define SPAN  5    // row-groups (of 16 rows) per block: 12500*5 = 62500 exact

typedef float f32x4 __attribute__((ext_vector_type(4)));
typedef float f32x2 __attribute__((ext_vector_type(2)));

__device__ __forceinline__ float sq4(f32x4 a, f32x4 b) {
    float d0 = a.x - b.x, d1 = a.y - b.y, d2 = a.z - b.z, d3 = a.w - b.w;
    return d0 * d0 + d1 * d1 + d2 * d2 + d3 * d3;
}

__global__ __launch_bounds__(BLOCK) void dcl_main(
    const float* __restrict__ recon_x,
    const float* __restrict__ x,
    const int* __restrict__ assign,
    const float* __restrict__ centers,
    float* __restrict__ ws)
{
    const int t   = threadIdx.x;
    const int r   = t >> 4;        // row within 16-row group: 0..15
    const int col = (t & 15) * 4;  // float4 slot within row
    const int g0  = blockIdx.x * SPAN;

    const int fbase = g0 * 1024 + r * 64 + col;
    const int abase = g0 * 16 + r;

    // issue all NT streaming loads up front (named vars -> stay in VGPRs)
    const f32x4 xv0 = __builtin_nontemporal_load((const f32x4*)(x + fbase));
    const f32x4 xv1 = __builtin_nontemporal_load((const f32x4*)(x + fbase + 1024));
    const f32x4 xv2 = __builtin_nontemporal_load((const f32x4*)(x + fbase + 2048));
    const f32x4 xv3 = __builtin_nontemporal_load((const f32x4*)(x + fbase + 3072));
    const f32x4 xv4 = __builtin_nontemporal_load((const f32x4*)(x + fbase + 4096));
    const f32x4 rv0 = __builtin_nontemporal_load((const f32x4*)(recon_x + fbase));
    const f32x4 rv1 = __builtin_nontemporal_load((const f32x4*)(recon_x + fbase + 1024));
    const f32x4 rv2 = __builtin_nontemporal_load((const f32x4*)(recon_x + fbase + 2048));
    const f32x4 rv3 = __builtin_nontemporal_load((const f32x4*)(recon_x + fbase + 3072));
    const f32x4 rv4 = __builtin_nontemporal_load((const f32x4*)(recon_x + fbase + 4096));

    const int c0 = assign[abase];
    const int c1 = assign[abase + 16];
    const int c2 = assign[abase + 32];
    const int c3 = assign[abase + 48];
    const int c4 = assign[abase + 64];

    const f32x4 cv0 = *(const f32x4*)(centers + c0 * DCOLS + col);
    const f32x4 cv1 = *(const f32x4*)(centers + c1 * DCOLS + col);
    const f32x4 cv2 = *(const f32x4*)(centers + c2 * DCOLS + col);
    const f32x4 cv3 = *(const f32x4*)(centers + c3 * DCOLS + col);
    const f32x4 cv4 = *(const f32x4*)(centers + c4 * DCOLS + col);

    float ra0 = sq4(rv0, xv0) + sq4(rv2, xv2);
    float ra1 = sq4(rv1, xv1) + sq4(rv3, xv3);
    ra0 += sq4(rv4, xv4);
    float ca0 = sq4(xv0, cv0) + sq4(xv2, cv2);
    float ca1 = sq4(xv1, cv1) + sq4(xv3, cv3);
    ca0 += sq4(xv4, cv4);

    float racc = ra0 + ra1;
    float cacc = ca0 + ca1;

    // wave-64 butterfly reduce
    #pragma unroll
    for (int off = 32; off > 0; off >>= 1) {
        racc += __shfl_down(racc, off);
        cacc += __shfl_down(cacc, off);
    }

    __shared__ float wsum_r[BLOCK / 64];
    __shared__ float wsum_c[BLOCK / 64];
    const int wave = t >> 6;
    if ((t & 63) == 0) {
        wsum_r[wave] = racc;
        wsum_c[wave] = cacc;
    }
    __syncthreads();

    if (t == 0) {
        float R = 0.0f, C = 0.0f;
        #pragma unroll
        for (int w = 0; w < BLOCK / 64; ++w) { R += wsum_r[w]; C += wsum_c[w]; }
        f32x2 p;
        p.x = R; p.y = C;
        __builtin_nontemporal_store(p, (f32x2*)(ws + 2 * blockIdx.x));
    }
}

__global__ __launch_bounds__(1024) void dcl_reduce(
    const float* __restrict__ ws,
    float* __restrict__ out)
{
    const int t = threadIdx.x;
    float R = 0.0f, C = 0.0f;
    for (int i = t; i < GRID; i += 1024) {
        const f32x2 p = *(const f32x2*)(ws + 2 * i);
        R += p.x; C += p.y;
    }

    #pragma unroll
    for (int off = 32; off > 0; off >>= 1) {
        R += __shfl_down(R, off);
        C += __shfl_down(C, off);
    }

    __shared__ float sr[16], sc[16];
    const int wave = t >> 6;
    if ((t & 63) == 0) { sr[wave] = R; sc[wave] = C; }
    __syncthreads();

    if (t == 0) {
        float Rt = 0.0f, Ct = 0.0f;
        #pragma unroll
        for (int w = 0; w < 16; ++w) { Rt += sr[w]; Ct += sc[w]; }
        out[0] = Rt + Ct;   // ALPHA=BETA=1
        out[1] = Rt;
        out[2] = Ct;
    }
}

extern "C" void kernel_launch(void* const* d_in, const int* in_sizes, int n_in,
                              void* d_out, int out_size, void* d_ws, size_t ws_size,
                              hipStream_t stream) {
    const float* recon_x = (const float*)d_in[0];
    const float* x       = (const float*)d_in[1];
    const int*   assign  = (const int*)d_in[2];
    const float* centers = (const float*)d_in[3];
    float* out = (float*)d_out;
    float* ws  = (float*)d_ws;

    dcl_main<<<GRID, BLOCK, 0, stream>>>(recon_x, x, assign, centers, ws);
    dcl_reduce<<<1, 1024, 0, stream>>>(ws, out);
}